// Round 8
// baseline (251.498 us; speedup 1.0000x reference)
//
#include <hip/hip_runtime.h>
#include <hip/hip_bf16.h>

// SingleHeadAttention: B=4, S=4096, H=1024, D=64. fp32 I/O, bf16 MFMA compute.
//
// k0: convert Wq/Wk/Wv/Wo fp32 -> bf16 (ws)
// k1: fused QKV proj, barrier-free streaming GEMM: A-frags read direct
//     global->reg (no LDS, no __syncthreads). 1024 blk x 256 thr (16-row
//     blocks, 4 waves = 4 col-groups, 4 blocks/CU). x rows L1-broadcast
//     across waves; weights stream from L2. [re-landed from R2 — its failure
//     was the k4 OOB bug, fixed in R7]
// k2: split-K causal flash: 512-key chunks (CHT=8), reg-prefetch double buffer
// k3: merge partials (qb >= 8)
// k4: Y = O @ Wo^T (fp32 out). R7 fix: Wo row stride is HDIM=64 (was HID:
//     OOB reads past the 64K-element Wob buffer — the session-long failure).
// Opart/Ml live in d_out as scratch (flash writes, merge reads, out_proj —
// the final kernel — overwrites the entire out buffer with Y; stream-ordered).

typedef __attribute__((ext_vector_type(8))) __bf16 bf16x8;
typedef __attribute__((ext_vector_type(4))) float f32x4;

#define BATCH 4
#define SEQ   4096
#define HID   1024
#define HDIM  64
#define CHT   8           // 64-key tiles per split-K chunk
#define NCMAX 8           // max chunks per Q-tile

__device__ __forceinline__ unsigned short f2bf(float f) {
  unsigned u = __builtin_bit_cast(unsigned, f);
  u += 0x7fffu + ((u >> 16) & 1u);          // RTN
  return (unsigned short)(u >> 16);
}
__device__ __forceinline__ float bf2f(unsigned short u) {
  unsigned v = ((unsigned)u) << 16;
  return __builtin_bit_cast(float, v);
}
__device__ __forceinline__ __bf16 f2bf16(float f) {
  unsigned short us = f2bf(f);
  return __builtin_bit_cast(__bf16, us);
}
__device__ __forceinline__ bf16x8 pack8(f32x4 a, f32x4 b) {
  bf16x8 r;
  r[0] = f2bf16(a[0]); r[1] = f2bf16(a[1]); r[2] = f2bf16(a[2]); r[3] = f2bf16(a[3]);
  r[4] = f2bf16(b[0]); r[5] = f2bf16(b[1]); r[6] = f2bf16(b[2]); r[7] = f2bf16(b[3]);
  return r;
}

// ---------------- k0: weight conversion ----------------
__global__ __launch_bounds__(256) void convert_w(
    const float* __restrict__ Wq, const float* __restrict__ Wk,
    const float* __restrict__ Wv, const float* __restrict__ Wo,
    unsigned short* __restrict__ q, unsigned short* __restrict__ k,
    unsigned short* __restrict__ v, unsigned short* __restrict__ o) {
  const int gid = blockIdx.x * 256 + threadIdx.x;
  const int mat = gid >> 16, idx = gid & 0xFFFF;
  const float* s = (mat == 0) ? Wq : (mat == 1) ? Wk : (mat == 2) ? Wv : Wo;
  unsigned short* d = (mat == 0) ? q : (mat == 1) ? k : (mat == 2) ? v : o;
  d[idx] = f2bf(s[idx]);
}

// ---------------- k1: fused QKV projection (barrier-free streaming) ----------------
// grid 1024 x 256 thr. Block = 16 rows. Wave w = col-group (cols w*16..w*16+15).
// Per wave: 16 rows x 16 cols x 3 matrices, K=1024 streamed in 32-wide steps.
// No LDS, no barriers: A-frags loaded global->reg (all 4 waves read the same
// 16 rows -> L1 broadcast); B-frags stream from L2 (384 KB/XCD resident).
__global__ __launch_bounds__(256) void qkv_proj(
    const float* __restrict__ x,
    const unsigned short* __restrict__ Wqb,
    const unsigned short* __restrict__ Wkb,
    const unsigned short* __restrict__ Wvb,
    unsigned short* __restrict__ Q,
    unsigned short* __restrict__ K,
    unsigned short* __restrict__ Vt) {
  const int mb   = blockIdx.x;          // 16-row tile
  const int tid  = threadIdx.x;
  const int lane = tid & 63;
  const int wave = tid >> 6;            // 0..3 : 16-col group
  const int quad = lane >> 4;
  const int l15  = lane & 15;

  const int arow = mb * 16 + l15;                    // A row this lane reads
  const float* xp = x + (size_t)arow * HID + quad * 8;

  const int col = wave * 16 + l15;                   // output col this lane owns
  const unsigned short* bq = Wqb + (size_t)col * HID + quad * 8;
  const unsigned short* bk = Wkb + (size_t)col * HID + quad * 8;
  const unsigned short* bv = Wvb + (size_t)col * HID + quad * 8;

  const f32x4 zero = {0.f, 0.f, 0.f, 0.f};
  f32x4 accq = zero, acck = zero, accv = zero;

#pragma unroll 2
  for (int kk = 0; kk < HID; kk += 32) {
    f32x4 alo = *reinterpret_cast<const f32x4*>(xp + kk);
    f32x4 ahi = *reinterpret_cast<const f32x4*>(xp + kk + 4);
    bf16x8 b0 = *reinterpret_cast<const bf16x8*>(bq + kk);
    bf16x8 b1 = *reinterpret_cast<const bf16x8*>(bk + kk);
    bf16x8 b2 = *reinterpret_cast<const bf16x8*>(bv + kk);
    bf16x8 a  = pack8(alo, ahi);
    accq = __builtin_amdgcn_mfma_f32_16x16x32_bf16(a, b0, accq, 0, 0, 0);
    acck = __builtin_amdgcn_mfma_f32_16x16x32_bf16(a, b1, acck, 0, 0, 0);
    accv = __builtin_amdgcn_mfma_f32_16x16x32_bf16(a, b2, accv, 0, 0, 0);
  }

  // C layout: col=l15(+wave*16), row=quad*4+r
  const int row0 = mb * 16 + quad * 4;
#pragma unroll
  for (int r = 0; r < 4; ++r) {
    Q[(size_t)(row0 + r) * HDIM + col] = f2bf(accq[r]);
    K[(size_t)(row0 + r) * HDIM + col] = f2bf(acck[r]);
  }
#pragma unroll
  for (int r = 0; r < 4; ++r) {
    const int row = row0 + r;                        // global seq index
    const int bb = row >> 12, sl = row & 4095;
    Vt[(size_t)bb * HDIM * SEQ + (size_t)col * SEQ + sl] = f2bf(accv[r]);
  }
}

// ---------------- k2: split-K causal flash, reg-prefetch dbuf ----------------
#define LSTR 72   // 64 + 8 pad (16B-aligned rows)

__global__ __launch_bounds__(256) void flash_splitk(
    const unsigned short* __restrict__ Qg,
    const unsigned short* __restrict__ Kg,
    const unsigned short* __restrict__ Vt,
    unsigned short* __restrict__ Og,
    unsigned short* __restrict__ Opart,
    float2* __restrict__ Ml) {
  const int qb = blockIdx.x;
  const int b  = blockIdx.y;
  const int c  = blockIdx.z;
  const int nc = (qb >> 3) + 1;          // ceil((qb+1)/CHT) for CHT=8
  if (c >= nc) return;
  const int j0 = c * CHT;
  const int j1 = min(j0 + CHT, qb + 1);

  const int tid  = threadIdx.x;
  const int lane = tid & 63;
  const int wave = tid >> 6;
  const int quad = lane >> 4;
  const int l15  = lane & 15;

  __shared__ unsigned short kt[64 * LSTR];       // K tile [key][dim]
  __shared__ unsigned short vt[64 * LSTR];       // V tile [dim][key]
  __shared__ unsigned short pt[4][16 * LSTR];    // per-wave P [qrow][key]

  const size_t base  = (size_t)b * SEQ * HDIM;
  const size_t baseT = (size_t)b * HDIM * SEQ;
  const int qrow0 = qb * 64 + wave * 16;

  bf16x8 aq[2];
  {
    const unsigned short* qp = Qg + base + (size_t)(qrow0 + l15) * HDIM + quad * 8;
    aq[0] = *reinterpret_cast<const bf16x8*>(qp);
    aq[1] = *reinterpret_cast<const bf16x8*>(qp + 32);
  }

  f32x4 o[4];
  const f32x4 zero = {0.f, 0.f, 0.f, 0.f};
#pragma unroll
  for (int n = 0; n < 4; ++n) o[n] = zero;
  float m_i[4], l_i[4];
#pragma unroll
  for (int r = 0; r < 4; ++r) { m_i[r] = -__builtin_inff(); l_i[r] = 0.f; }

  unsigned short* pw = pt[wave];
  const int srow = tid >> 2, sc0 = (tid & 3) * 16;   // staging coords
  const unsigned short* kb = Kg + base;
  const unsigned short* vb = Vt + baseT;

  // softmax scale folded into exp2: p = 2^(s*C - m*C),  C = 0.125*log2(e)
  const float C = 0.125f * 1.44269504f;

  // prologue: stage tile j0
  uint4 pk0, pk1, pv0, pv1;
  {
    const uint4* kp = reinterpret_cast<const uint4*>(kb + (size_t)(j0 * 64 + srow) * HDIM + sc0);
    pk0 = kp[0]; pk1 = kp[1];
    const uint4* vp = reinterpret_cast<const uint4*>(vb + (size_t)srow * SEQ + j0 * 64 + sc0);
    pv0 = vp[0]; pv1 = vp[1];
    *reinterpret_cast<uint4*>(&kt[srow * LSTR + sc0])     = pk0;
    *reinterpret_cast<uint4*>(&kt[srow * LSTR + sc0 + 8]) = pk1;
    *reinterpret_cast<uint4*>(&vt[srow * LSTR + sc0])     = pv0;
    *reinterpret_cast<uint4*>(&vt[srow * LSTR + sc0 + 8]) = pv1;
  }

  for (int j = j0; j < j1; ++j) {
    __syncthreads();                       // publish LDS tile j
    const bool pre = (j + 1 < j1);
    if (pre) {                             // issue loads for tile j+1 now
      const uint4* kp = reinterpret_cast<const uint4*>(kb + (size_t)((j + 1) * 64 + srow) * HDIM + sc0);
      pk0 = kp[0]; pk1 = kp[1];
      const uint4* vp = reinterpret_cast<const uint4*>(vb + (size_t)srow * SEQ + (j + 1) * 64 + sc0);
      pv0 = vp[0]; pv1 = vp[1];
    }

    f32x4 s[4];
#pragma unroll
    for (int n = 0; n < 4; ++n) s[n] = zero;
#pragma unroll
    for (int ks = 0; ks < 2; ++ks) {
#pragma unroll
      for (int n = 0; n < 4; ++n) {
        bf16x8 bk = *reinterpret_cast<const bf16x8*>(&kt[(n * 16 + l15) * LSTR + ks * 32 + quad * 8]);
        s[n] = __builtin_amdgcn_mfma_f32_16x16x32_bf16(aq[ks], bk, s[n], 0, 0, 0);
      }
    }

    if (j == qb) {                         // causal mask (raw-score units)
#pragma unroll
      for (int n = 0; n < 4; ++n) {
        const int col = n * 16 + l15;
#pragma unroll
        for (int r = 0; r < 4; ++r) {
          const int rowl = wave * 16 + quad * 4 + r;
          if (col > rowl) s[n][r] = -__builtin_inff();
        }
      }
    }

    float mnew[4], alpha[4], mC[4];
#pragma unroll
    for (int r = 0; r < 4; ++r) {
      float v = fmaxf(fmaxf(s[0][r], s[1][r]), fmaxf(s[2][r], s[3][r]));
#pragma unroll
      for (int off = 1; off < 16; off <<= 1) v = fmaxf(v, __shfl_xor(v, off, 64));
      mnew[r]  = fmaxf(m_i[r], v);
      alpha[r] = __builtin_amdgcn_exp2f((m_i[r] - mnew[r]) * C);
      mC[r]    = mnew[r] * C;
    }
    float p[4][4];
#pragma unroll
    for (int n = 0; n < 4; ++n)
#pragma unroll
      for (int r = 0; r < 4; ++r)
        p[n][r] = __builtin_amdgcn_exp2f(__builtin_fmaf(s[n][r], C, -mC[r]));
#pragma unroll
    for (int r = 0; r < 4; ++r) {
      float v = (p[0][r] + p[1][r]) + (p[2][r] + p[3][r]);
#pragma unroll
      for (int off = 1; off < 16; off <<= 1) v += __shfl_xor(v, off, 64);
      l_i[r] = l_i[r] * alpha[r] + v;
      m_i[r] = mnew[r];
    }
#pragma unroll
    for (int n = 0; n < 4; ++n)
#pragma unroll
      for (int r = 0; r < 4; ++r) o[n][r] *= alpha[r];

#pragma unroll
    for (int n = 0; n < 4; ++n)
#pragma unroll
      for (int r = 0; r < 4; ++r)
        pw[(quad * 4 + r) * LSTR + n * 16 + l15] = f2bf(p[n][r]);

#pragma unroll
    for (int ks = 0; ks < 2; ++ks) {
      bf16x8 ap = *reinterpret_cast<const bf16x8*>(&pw[l15 * LSTR + ks * 32 + quad * 8]);
#pragma unroll
      for (int n = 0; n < 4; ++n) {
        bf16x8 bv = *reinterpret_cast<const bf16x8*>(&vt[(n * 16 + l15) * LSTR + ks * 32 + quad * 8]);
        o[n] = __builtin_amdgcn_mfma_f32_16x16x32_bf16(ap, bv, o[n], 0, 0, 0);
      }
    }

    __syncthreads();                       // all waves done reading kt/vt
    if (pre) {                             // drain prefetch into LDS
      *reinterpret_cast<uint4*>(&kt[srow * LSTR + sc0])     = pk0;
      *reinterpret_cast<uint4*>(&kt[srow * LSTR + sc0 + 8]) = pk1;
      *reinterpret_cast<uint4*>(&vt[srow * LSTR + sc0])     = pv0;
      *reinterpret_cast<uint4*>(&vt[srow * LSTR + sc0 + 8]) = pv1;
    }
  }

  if (nc == 1) {
#pragma unroll
    for (int n = 0; n < 4; ++n)
#pragma unroll
      for (int r = 0; r < 4; ++r) {
        const int row = qrow0 + quad * 4 + r;
        const int col = n * 16 + l15;
        Og[base + (size_t)row * HDIM + col] = f2bf(o[n][r] / l_i[r]);
      }
  } else {
    const int slot = ((b * 64 + qb) << 3) + c;
#pragma unroll
    for (int n = 0; n < 4; ++n)
#pragma unroll
      for (int r = 0; r < 4; ++r) {
        const int rowl = wave * 16 + quad * 4 + r;
        const int col  = n * 16 + l15;
        Opart[(size_t)slot * 4096 + rowl * 64 + col] = f2bf(o[n][r]);
      }
    if (l15 == 0) {
#pragma unroll
      for (int r = 0; r < 4; ++r) {
        const int rowl = wave * 16 + quad * 4 + r;
        Ml[slot * 64 + rowl] = make_float2(m_i[r], l_i[r]);
      }
    }
  }
}

// ---------------- k3: merge split-K partials (qb >= 8) ----------------
__global__ __launch_bounds__(256) void merge_splitk(
    const unsigned short* __restrict__ Opart,
    const float2* __restrict__ Ml,
    unsigned short* __restrict__ Og) {
  const int qb = blockIdx.x;
  if (qb < CHT) return;
  const int b  = blockIdx.y;
  const int nc = (qb >> 3) + 1;
  const int row = threadIdx.x >> 2;
  const int cg  = (threadIdx.x & 3) * 16;
  const int slot0 = (b * 64 + qb) << 3;

  float m[NCMAX], l[NCMAX];
  float M = -__builtin_inff();
  for (int c = 0; c < nc; ++c) {
    float2 ml = Ml[(slot0 + c) * 64 + row];
    m[c] = ml.x; l[c] = ml.y;
    M = fmaxf(M, m[c]);
  }
  const float C = 0.125f * 1.44269504f;
  float L = 0.f, acc[16];
#pragma unroll
  for (int i = 0; i < 16; ++i) acc[i] = 0.f;
  for (int c = 0; c < nc; ++c) {
    const float w = __builtin_amdgcn_exp2f((m[c] - M) * C);
    L += w * l[c];
    const unsigned short* p = Opart + (size_t)(slot0 + c) * 4096 + row * 64 + cg;
    uint4 u0 = *reinterpret_cast<const uint4*>(p);
    uint4 u1 = *reinterpret_cast<const uint4*>(p + 8);
    const unsigned* uu = &u0.x;
#pragma unroll
    for (int i = 0; i < 4; ++i) {
      acc[2 * i]     += w * bf2f((unsigned short)(uu[i] & 0xFFFF));
      acc[2 * i + 1] += w * bf2f((unsigned short)(uu[i] >> 16));
    }
    const unsigned* vv = &u1.x;
#pragma unroll
    for (int i = 0; i < 4; ++i) {
      acc[8 + 2 * i]     += w * bf2f((unsigned short)(vv[i] & 0xFFFF));
      acc[8 + 2 * i + 1] += w * bf2f((unsigned short)(vv[i] >> 16));
    }
  }
  const float inv = 1.f / L;
  uint4 o0, o1;
  unsigned* po = &o0.x;
#pragma unroll
  for (int i = 0; i < 4; ++i)
    po[i] = (unsigned)f2bf(acc[2 * i] * inv) | ((unsigned)f2bf(acc[2 * i + 1] * inv) << 16);
  unsigned* p1 = &o1.x;
#pragma unroll
  for (int i = 0; i < 4; ++i)
    p1[i] = (unsigned)f2bf(acc[8 + 2 * i] * inv) | ((unsigned)f2bf(acc[8 + 2 * i + 1] * inv) << 16);
  unsigned short* dst = Og + (size_t)b * SEQ * HDIM + (size_t)(qb * 64 + row) * HDIM + cg;
  *reinterpret_cast<uint4*>(dst)     = o0;
  *reinterpret_cast<uint4*>(dst + 8) = o1;
}

// ---------------- k4: output projection Y = O @ Wo^T (fp32 out) ----------------
// Wo is [HID][HDIM] row-major: row stride HDIM=64. B-frag for output col h:
// Wob[h*HDIM + k] with k = quad*8 (+32 for the second K=32 step).
__global__ __launch_bounds__(256) void out_proj(
    const unsigned short* __restrict__ O,
    const unsigned short* __restrict__ Wob,
    float* __restrict__ Y) {
  const int nb   = blockIdx.x;
  const int mb   = blockIdx.y;
  const int lane = threadIdx.x & 63;
  const int wave = threadIdx.x >> 6;
  const int quad = lane >> 4;
  const int l15  = lane & 15;
  const int row0 = mb * 64 + wave * 16;

  f32x4 acc[4];
  const f32x4 zero = {0.f, 0.f, 0.f, 0.f};
#pragma unroll
  for (int n = 0; n < 4; ++n) acc[n] = zero;

  const unsigned short* op = O + (size_t)(row0 + l15) * HDIM + quad * 8;
  bf16x8 a0 = *reinterpret_cast<const bf16x8*>(op);
  bf16x8 a1 = *reinterpret_cast<const bf16x8*>(op + 32);
#pragma unroll
  for (int n = 0; n < 4; ++n) {
    const int col = nb * 64 + n * 16 + l15;
    const unsigned short* wp = Wob + (size_t)col * HDIM + quad * 8;   // stride HDIM (R7 fix)
    bf16x8 b0 = *reinterpret_cast<const bf16x8*>(wp);
    bf16x8 b1 = *reinterpret_cast<const bf16x8*>(wp + 32);
    acc[n] = __builtin_amdgcn_mfma_f32_16x16x32_bf16(a0, b0, acc[n], 0, 0, 0);
    acc[n] = __builtin_amdgcn_mfma_f32_16x16x32_bf16(a1, b1, acc[n], 0, 0, 0);
  }
#pragma unroll
  for (int n = 0; n < 4; ++n)
#pragma unroll
    for (int r = 0; r < 4; ++r) {
      const int row = row0 + quad * 4 + r;
      const int col = nb * 64 + n * 16 + l15;
      Y[(size_t)row * HID + col] = acc[n][r];
    }
}

extern "C" void kernel_launch(void* const* d_in, const int* in_sizes, int n_in,
                              void* d_out, int out_size, void* d_ws, size_t ws_size,
                              hipStream_t stream) {
  const float* x  = (const float*)d_in[0];
  const float* Wq = (const float*)d_in[1];
  const float* Wk = (const float*)d_in[2];
  const float* Wv = (const float*)d_in[3];
  const float* Wo = (const float*)d_in[4];
  float* Y = (float*)d_out;

  const size_t qkv_elems = (size_t)BATCH * SEQ * HDIM;       // 1M
  const size_t w_elems   = (size_t)HDIM * HID;               // 64K
  unsigned short* Q     = (unsigned short*)d_ws;
  unsigned short* K     = Q + qkv_elems;
  unsigned short* Vt    = K + qkv_elems;
  unsigned short* O     = Vt + qkv_elems;
  unsigned short* Wqb   = O + qkv_elems;
  unsigned short* Wkb   = Wqb + w_elems;
  unsigned short* Wvb   = Wkb + w_elems;
  unsigned short* Wob   = Wvb + w_elems;
  // ws use: 4x 2MB QKVO + 0.5MB weights = 8.5 MB.
  // Split-K partials live in d_out as scratch (64 MB fp32 buffer; partials
  // need 17 MB). Safe: flash writes Opart/Ml, merge reads them, then out_proj
  // (last kernel, same stream) overwrites the ENTIRE out buffer with Y.
  unsigned short* Opart = (unsigned short*)d_out;             // 2048 slots x 4096 bf16 = 16 MB
  float2*         Ml    = (float2*)(Opart + (size_t)2048 * 4096);  // 128K float2 = 1 MB

  convert_w   <<<1024,               256, 0, stream>>>(Wq, Wk, Wv, Wo, Wqb, Wkb, Wvb, Wob);
  qkv_proj    <<<1024,               256, 0, stream>>>(x, Wqb, Wkb, Wvb, Q, K, Vt);
  flash_splitk<<<dim3(64, 4, NCMAX), 256, 0, stream>>>(Q, K, Vt, O, Opart, Ml);
  merge_splitk<<<dim3(64, 4),        256, 0, stream>>>(Opart, Ml, O);
  out_proj    <<<dim3(16, 256),      256, 0, stream>>>(O, Wob, Y);
}

// Round 9
// 203.034 us; speedup vs baseline: 1.2387x; 1.2387x over previous
//
#include <hip/hip_runtime.h>
#include <hip/hip_bf16.h>

// SingleHeadAttention: B=4, S=4096, H=1024, D=64. fp32 I/O, bf16 MFMA compute.
//
// k0: convert Wq/Wk/Wv/Wo fp32 -> bf16 (ws)
// k1: fused QKV proj v3: BOTH x and W staged in LDS via coalesced
//     global_load_lds (full 128B lines, pre-swizzled global sources),
//     K-chunk 64, double-buffered, 512 blk x 256 thr (M=32, 2 blocks/CU).
//     R8 lesson: kernel is L2-transaction-bound on scattered W reads
//     (16 lines/instr, 8x line re-reads); staging W cuts requests ~4x.
// k2: split-K causal flash: 512-key chunks (CHT=8), reg-prefetch double buffer
// k3: merge partials (qb >= 8)
// k4: Y = O @ Wo^T (fp32 out). Wo row stride HDIM=64 (R7 fix).
// Opart/Ml live in d_out as scratch (flash writes, merge reads, out_proj —
// the final kernel — overwrites the entire out buffer with Y; stream-ordered).

typedef __attribute__((ext_vector_type(8))) __bf16 bf16x8;
typedef __attribute__((ext_vector_type(4))) float f32x4;

#define BATCH 4
#define SEQ   4096
#define HID   1024
#define HDIM  64
#define CHT   8           // 64-key tiles per split-K chunk
#define NCMAX 8           // max chunks per Q-tile

__device__ __forceinline__ unsigned short f2bf(float f) {
  unsigned u = __builtin_bit_cast(unsigned, f);
  u += 0x7fffu + ((u >> 16) & 1u);          // RTN
  return (unsigned short)(u >> 16);
}
__device__ __forceinline__ float bf2f(unsigned short u) {
  unsigned v = ((unsigned)u) << 16;
  return __builtin_bit_cast(float, v);
}
__device__ __forceinline__ __bf16 f2bf16(float f) {
  unsigned short us = f2bf(f);
  return __builtin_bit_cast(__bf16, us);
}
__device__ __forceinline__ bf16x8 pack8(f32x4 a, f32x4 b) {
  bf16x8 r;
  r[0] = f2bf16(a[0]); r[1] = f2bf16(a[1]); r[2] = f2bf16(a[2]); r[3] = f2bf16(a[3]);
  r[4] = f2bf16(b[0]); r[5] = f2bf16(b[1]); r[6] = f2bf16(b[2]); r[7] = f2bf16(b[3]);
  return r;
}

// ---------------- k0: weight conversion ----------------
__global__ __launch_bounds__(256) void convert_w(
    const float* __restrict__ Wq, const float* __restrict__ Wk,
    const float* __restrict__ Wv, const float* __restrict__ Wo,
    unsigned short* __restrict__ q, unsigned short* __restrict__ k,
    unsigned short* __restrict__ v, unsigned short* __restrict__ o) {
  const int gid = blockIdx.x * 256 + threadIdx.x;
  const int mat = gid >> 16, idx = gid & 0xFFFF;
  const float* s = (mat == 0) ? Wq : (mat == 1) ? Wk : (mat == 2) ? Wv : Wo;
  unsigned short* d = (mat == 0) ? q : (mat == 1) ? k : (mat == 2) ? v : o;
  d[idx] = f2bf(s[idx]);
}

// ---------------- k1: fused QKV projection (x + W LDS-staged, K-chunk 64) ----
// grid 512 x 256 thr. Block = 32 rows, all 192 output cols. Wave w: row-tile
// rt=w>>1 (16 rows), col-half nh=w&1 (32 of 64 cols per matrix). Per K=64 tile:
//  - x tile [32][64] fp32 staged as 16B chunks, LDS[row][p] = global chunk
//    p^(row&7) (low-3-bit XOR; bit3 = K-half preserved). 2 issues.
//  - W tile per z [64 cols][64 k] bf16 (128B rows), LDS[col][p] = global chunk
//    p^(col&7). 2 issues per z. Full-line coalesced (8 lanes cover one line).
//  - compute: 2 K=32 sub-steps x 6 MFMAs (3z x 2 n2).
__global__ __launch_bounds__(256) void qkv_proj(
    const float* __restrict__ x,
    const unsigned short* __restrict__ Wqb,
    const unsigned short* __restrict__ Wkb,
    const unsigned short* __restrict__ Wvb,
    unsigned short* __restrict__ Q,
    unsigned short* __restrict__ K,
    unsigned short* __restrict__ Vt) {
  const int mb   = blockIdx.x;          // 32-row tile
  const int tid  = threadIdx.x;
  const int lane = tid & 63;
  const int wave = tid >> 6;
  const int quad = lane >> 4;
  const int l15  = lane & 15;
  const int rt   = wave >> 1;           // 0,1
  const int nh   = wave & 1;            // 0,1
  const int ar   = rt * 16 + l15;       // local row this lane reads for A
  const int row0 = mb * 32 + rt * 16;

  __shared__ float          xs[2][32 * 64];       // 8KB per buf
  __shared__ unsigned short wl[2][3 * 64 * 64];   // 24KB per buf

  const unsigned short* Ws[3] = {Wqb, Wkb, Wvb};

  f32x4 acc[3][2];
  const f32x4 zero = {0.f, 0.f, 0.f, 0.f};
#pragma unroll
  for (int z = 0; z < 3; ++z)
#pragma unroll
    for (int n2 = 0; n2 < 2; ++n2) acc[z][n2] = zero;

  // ---- staging coordinates (per thread, per issue) ----
  // x: slot = j*256 + tid -> row = slot>>4, p = slot&15, src chunk = p^(row&7)
  const int xrow0 = tid >> 4;            // issue 0 row (0..15)
  const int xp    = tid & 15;
  const int xg0   = (xp & 8) | ((xp & 7) ^ (xrow0 & 7));
  const int xrow1 = xrow0 + 16;          // issue 1 row (16..31)
  const int xg1   = (xp & 8) | ((xp & 7) ^ (xrow1 & 7));
  const float* xsrc0 = x + (size_t)(mb * 32 + xrow0) * HID + xg0 * 4;
  const float* xsrc1 = x + (size_t)(mb * 32 + xrow1) * HID + xg1 * 4;
  // W: slot = j*256 + tid -> col = slot>>3, p = slot&7, src chunk = p^(col&7)
  const int wcol0 = tid >> 3;            // issue 0 col (0..31)
  const int wp    = tid & 7;
  const int wg0   = wp ^ (wcol0 & 7);
  const int wcol1 = wcol0 + 32;          // issue 1 col (32..63)
  const int wg1   = wp ^ (wcol1 & 7);

  // a-frag LDS fp32-chunk positions (XOR low 3 bits with ar&7)
  const int swz = ar & 7;

#define STAGE_TILE(buf, kk)                                                     \
  do {                                                                          \
    float* xb = &xs[buf][wave * 256];                                           \
    __builtin_amdgcn_global_load_lds(                                           \
        (const __attribute__((address_space(1))) void*)(xsrc0 + (kk)),          \
        (__attribute__((address_space(3))) void*)xb, 16, 0, 0);                 \
    __builtin_amdgcn_global_load_lds(                                           \
        (const __attribute__((address_space(1))) void*)(xsrc1 + (kk)),          \
        (__attribute__((address_space(3))) void*)(xb + 1024), 16, 0, 0);        \
    _Pragma("unroll")                                                           \
    for (int z = 0; z < 3; ++z) {                                               \
      unsigned short* wb = &wl[buf][z * 4096 + wave * 512];                     \
      __builtin_amdgcn_global_load_lds(                                         \
          (const __attribute__((address_space(1))) void*)(                      \
              Ws[z] + (size_t)wcol0 * HID + (kk) + wg0 * 8),                    \
          (__attribute__((address_space(3))) void*)wb, 16, 0, 0);               \
      __builtin_amdgcn_global_load_lds(                                         \
          (const __attribute__((address_space(1))) void*)(                      \
              Ws[z] + (size_t)wcol1 * HID + (kk) + wg1 * 8),                    \
          (__attribute__((address_space(3))) void*)(wb + 2048), 16, 0, 0);      \
    }                                                                           \
  } while (0)

  // prologue: stage tile kk=0 into buf 0
  STAGE_TILE(0, 0);

  for (int kk = 0; kk < HID; kk += 64) {
    const int buf = (kk >> 6) & 1;
    __syncthreads();                    // drains vmcnt -> tile kk visible
    if (kk + 64 < HID) STAGE_TILE(buf ^ 1, kk + 64);

#pragma unroll
    for (int sub = 0; sub < 2; ++sub) {
      const int c0 = sub * 8 + ((2 * quad)     ^ swz);
      const int c1 = sub * 8 + ((2 * quad + 1) ^ swz);
      f32x4 alo = *reinterpret_cast<const f32x4*>(&xs[buf][ar * 64 + c0 * 4]);
      f32x4 ahi = *reinterpret_cast<const f32x4*>(&xs[buf][ar * 64 + c1 * 4]);
      bf16x8 a = pack8(alo, ahi);
#pragma unroll
      for (int z = 0; z < 3; ++z)
#pragma unroll
        for (int n2 = 0; n2 < 2; ++n2) {
          const int col = nh * 32 + n2 * 16 + l15;
          const int wc  = (sub * 4 + quad) ^ (col & 7);
          bf16x8 b = *reinterpret_cast<const bf16x8*>(&wl[buf][z * 4096 + col * 64 + wc * 8]);
          acc[z][n2] = __builtin_amdgcn_mfma_f32_16x16x32_bf16(a, b, acc[z][n2], 0, 0, 0);
        }
    }
  }
#undef STAGE_TILE

  // epilogue: C layout col=l15(+offsets), row=quad*4+r
#pragma unroll
  for (int z = 0; z < 2; ++z) {
    unsigned short* Out = (z == 0) ? Q : K;
#pragma unroll
    for (int n2 = 0; n2 < 2; ++n2)
#pragma unroll
      for (int r = 0; r < 4; ++r) {
        const int row = row0 + quad * 4 + r;
        const int col = nh * 32 + n2 * 16 + l15;
        Out[(size_t)row * HDIM + col] = f2bf(acc[z][n2][r]);
      }
  }
#pragma unroll
  for (int n2 = 0; n2 < 2; ++n2)
#pragma unroll
    for (int r = 0; r < 4; ++r) {
      const int row = row0 + quad * 4 + r;          // global seq index
      const int col = nh * 32 + n2 * 16 + l15;      // dim
      const int bb = row >> 12, sl = row & 4095;
      Vt[(size_t)bb * HDIM * SEQ + (size_t)col * SEQ + sl] = f2bf(acc[2][n2][r]);
    }
}

// ---------------- k2: split-K causal flash, reg-prefetch dbuf ----------------
#define LSTR 72   // 64 + 8 pad (16B-aligned rows)

__global__ __launch_bounds__(256) void flash_splitk(
    const unsigned short* __restrict__ Qg,
    const unsigned short* __restrict__ Kg,
    const unsigned short* __restrict__ Vt,
    unsigned short* __restrict__ Og,
    unsigned short* __restrict__ Opart,
    float2* __restrict__ Ml) {
  const int qb = blockIdx.x;
  const int b  = blockIdx.y;
  const int c  = blockIdx.z;
  const int nc = (qb >> 3) + 1;          // ceil((qb+1)/CHT) for CHT=8
  if (c >= nc) return;
  const int j0 = c * CHT;
  const int j1 = min(j0 + CHT, qb + 1);

  const int tid  = threadIdx.x;
  const int lane = tid & 63;
  const int wave = tid >> 6;
  const int quad = lane >> 4;
  const int l15  = lane & 15;

  __shared__ unsigned short kt[64 * LSTR];       // K tile [key][dim]
  __shared__ unsigned short vt[64 * LSTR];       // V tile [dim][key]
  __shared__ unsigned short pt[4][16 * LSTR];    // per-wave P [qrow][key]

  const size_t base  = (size_t)b * SEQ * HDIM;
  const size_t baseT = (size_t)b * HDIM * SEQ;
  const int qrow0 = qb * 64 + wave * 16;

  bf16x8 aq[2];
  {
    const unsigned short* qp = Qg + base + (size_t)(qrow0 + l15) * HDIM + quad * 8;
    aq[0] = *reinterpret_cast<const bf16x8*>(qp);
    aq[1] = *reinterpret_cast<const bf16x8*>(qp + 32);
  }

  f32x4 o[4];
  const f32x4 zero = {0.f, 0.f, 0.f, 0.f};
#pragma unroll
  for (int n = 0; n < 4; ++n) o[n] = zero;
  float m_i[4], l_i[4];
#pragma unroll
  for (int r = 0; r < 4; ++r) { m_i[r] = -__builtin_inff(); l_i[r] = 0.f; }

  unsigned short* pw = pt[wave];
  const int srow = tid >> 2, sc0 = (tid & 3) * 16;   // staging coords
  const unsigned short* kb = Kg + base;
  const unsigned short* vb = Vt + baseT;

  // softmax scale folded into exp2: p = 2^(s*C - m*C),  C = 0.125*log2(e)
  const float C = 0.125f * 1.44269504f;

  // prologue: stage tile j0
  uint4 pk0, pk1, pv0, pv1;
  {
    const uint4* kp = reinterpret_cast<const uint4*>(kb + (size_t)(j0 * 64 + srow) * HDIM + sc0);
    pk0 = kp[0]; pk1 = kp[1];
    const uint4* vp = reinterpret_cast<const uint4*>(vb + (size_t)srow * SEQ + j0 * 64 + sc0);
    pv0 = vp[0]; pv1 = vp[1];
    *reinterpret_cast<uint4*>(&kt[srow * LSTR + sc0])     = pk0;
    *reinterpret_cast<uint4*>(&kt[srow * LSTR + sc0 + 8]) = pk1;
    *reinterpret_cast<uint4*>(&vt[srow * LSTR + sc0])     = pv0;
    *reinterpret_cast<uint4*>(&vt[srow * LSTR + sc0 + 8]) = pv1;
  }

  for (int j = j0; j < j1; ++j) {
    __syncthreads();                       // publish LDS tile j
    const bool pre = (j + 1 < j1);
    if (pre) {                             // issue loads for tile j+1 now
      const uint4* kp = reinterpret_cast<const uint4*>(kb + (size_t)((j + 1) * 64 + srow) * HDIM + sc0);
      pk0 = kp[0]; pk1 = kp[1];
      const uint4* vp = reinterpret_cast<const uint4*>(vb + (size_t)srow * SEQ + (j + 1) * 64 + sc0);
      pv0 = vp[0]; pv1 = vp[1];
    }

    f32x4 s[4];
#pragma unroll
    for (int n = 0; n < 4; ++n) s[n] = zero;
#pragma unroll
    for (int ks = 0; ks < 2; ++ks) {
#pragma unroll
      for (int n = 0; n < 4; ++n) {
        bf16x8 bk = *reinterpret_cast<const bf16x8*>(&kt[(n * 16 + l15) * LSTR + ks * 32 + quad * 8]);
        s[n] = __builtin_amdgcn_mfma_f32_16x16x32_bf16(aq[ks], bk, s[n], 0, 0, 0);
      }
    }

    if (j == qb) {                         // causal mask (raw-score units)
#pragma unroll
      for (int n = 0; n < 4; ++n) {
        const int col = n * 16 + l15;
#pragma unroll
        for (int r = 0; r < 4; ++r) {
          const int rowl = wave * 16 + quad * 4 + r;
          if (col > rowl) s[n][r] = -__builtin_inff();
        }
      }
    }

    float mnew[4], alpha[4], mC[4];
#pragma unroll
    for (int r = 0; r < 4; ++r) {
      float v = fmaxf(fmaxf(s[0][r], s[1][r]), fmaxf(s[2][r], s[3][r]));
#pragma unroll
      for (int off = 1; off < 16; off <<= 1) v = fmaxf(v, __shfl_xor(v, off, 64));
      mnew[r]  = fmaxf(m_i[r], v);
      alpha[r] = __builtin_amdgcn_exp2f((m_i[r] - mnew[r]) * C);
      mC[r]    = mnew[r] * C;
    }
    float p[4][4];
#pragma unroll
    for (int n = 0; n < 4; ++n)
#pragma unroll
      for (int r = 0; r < 4; ++r)
        p[n][r] = __builtin_amdgcn_exp2f(__builtin_fmaf(s[n][r], C, -mC[r]));
#pragma unroll
    for (int r = 0; r < 4; ++r) {
      float v = (p[0][r] + p[1][r]) + (p[2][r] + p[3][r]);
#pragma unroll
      for (int off = 1; off < 16; off <<= 1) v += __shfl_xor(v, off, 64);
      l_i[r] = l_i[r] * alpha[r] + v;
      m_i[r] = mnew[r];
    }
#pragma unroll
    for (int n = 0; n < 4; ++n)
#pragma unroll
      for (int r = 0; r < 4; ++r) o[n][r] *= alpha[r];

#pragma unroll
    for (int n = 0; n < 4; ++n)
#pragma unroll
      for (int r = 0; r < 4; ++r)
        pw[(quad * 4 + r) * LSTR + n * 16 + l15] = f2bf(p[n][r]);

#pragma unroll
    for (int ks = 0; ks < 2; ++ks) {
      bf16x8 ap = *reinterpret_cast<const bf16x8*>(&pw[l15 * LSTR + ks * 32 + quad * 8]);
#pragma unroll
      for (int n = 0; n < 4; ++n) {
        bf16x8 bv = *reinterpret_cast<const bf16x8*>(&vt[(n * 16 + l15) * LSTR + ks * 32 + quad * 8]);
        o[n] = __builtin_amdgcn_mfma_f32_16x16x32_bf16(ap, bv, o[n], 0, 0, 0);
      }
    }

    __syncthreads();                       // all waves done reading kt/vt
    if (pre) {                             // drain prefetch into LDS
      *reinterpret_cast<uint4*>(&kt[srow * LSTR + sc0])     = pk0;
      *reinterpret_cast<uint4*>(&kt[srow * LSTR + sc0 + 8]) = pk1;
      *reinterpret_cast<uint4*>(&vt[srow * LSTR + sc0])     = pv0;
      *reinterpret_cast<uint4*>(&vt[srow * LSTR + sc0 + 8]) = pv1;
    }
  }

  if (nc == 1) {
#pragma unroll
    for (int n = 0; n < 4; ++n)
#pragma unroll
      for (int r = 0; r < 4; ++r) {
        const int row = qrow0 + quad * 4 + r;
        const int col = n * 16 + l15;
        Og[base + (size_t)row * HDIM + col] = f2bf(o[n][r] / l_i[r]);
      }
  } else {
    const int slot = ((b * 64 + qb) << 3) + c;
#pragma unroll
    for (int n = 0; n < 4; ++n)
#pragma unroll
      for (int r = 0; r < 4; ++r) {
        const int rowl = wave * 16 + quad * 4 + r;
        const int col  = n * 16 + l15;
        Opart[(size_t)slot * 4096 + rowl * 64 + col] = f2bf(o[n][r]);
      }
    if (l15 == 0) {
#pragma unroll
      for (int r = 0; r < 4; ++r) {
        const int rowl = wave * 16 + quad * 4 + r;
        Ml[slot * 64 + rowl] = make_float2(m_i[r], l_i[r]);
      }
    }
  }
}

// ---------------- k3: merge split-K partials (qb >= 8) ----------------
__global__ __launch_bounds__(256) void merge_splitk(
    const unsigned short* __restrict__ Opart,
    const float2* __restrict__ Ml,
    unsigned short* __restrict__ Og) {
  const int qb = blockIdx.x;
  if (qb < CHT) return;
  const int b  = blockIdx.y;
  const int nc = (qb >> 3) + 1;
  const int row = threadIdx.x >> 2;
  const int cg  = (threadIdx.x & 3) * 16;
  const int slot0 = (b * 64 + qb) << 3;

  float m[NCMAX], l[NCMAX];
  float M = -__builtin_inff();
  for (int c = 0; c < nc; ++c) {
    float2 ml = Ml[(slot0 + c) * 64 + row];
    m[c] = ml.x; l[c] = ml.y;
    M = fmaxf(M, m[c]);
  }
  const float C = 0.125f * 1.44269504f;
  float L = 0.f, acc[16];
#pragma unroll
  for (int i = 0; i < 16; ++i) acc[i] = 0.f;
  for (int c = 0; c < nc; ++c) {
    const float w = __builtin_amdgcn_exp2f((m[c] - M) * C);
    L += w * l[c];
    const unsigned short* p = Opart + (size_t)(slot0 + c) * 4096 + row * 64 + cg;
    uint4 u0 = *reinterpret_cast<const uint4*>(p);
    uint4 u1 = *reinterpret_cast<const uint4*>(p + 8);
    const unsigned* uu = &u0.x;
#pragma unroll
    for (int i = 0; i < 4; ++i) {
      acc[2 * i]     += w * bf2f((unsigned short)(uu[i] & 0xFFFF));
      acc[2 * i + 1] += w * bf2f((unsigned short)(uu[i] >> 16));
    }
    const unsigned* vv = &u1.x;
#pragma unroll
    for (int i = 0; i < 4; ++i) {
      acc[8 + 2 * i]     += w * bf2f((unsigned short)(vv[i] & 0xFFFF));
      acc[8 + 2 * i + 1] += w * bf2f((unsigned short)(vv[i] >> 16));
    }
  }
  const float inv = 1.f / L;
  uint4 o0, o1;
  unsigned* po = &o0.x;
#pragma unroll
  for (int i = 0; i < 4; ++i)
    po[i] = (unsigned)f2bf(acc[2 * i] * inv) | ((unsigned)f2bf(acc[2 * i + 1] * inv) << 16);
  unsigned* p1 = &o1.x;
#pragma unroll
  for (int i = 0; i < 4; ++i)
    p1[i] = (unsigned)f2bf(acc[8 + 2 * i] * inv) | ((unsigned)f2bf(acc[8 + 2 * i + 1] * inv) << 16);
  unsigned short* dst = Og + (size_t)b * SEQ * HDIM + (size_t)(qb * 64 + row) * HDIM + cg;
  *reinterpret_cast<uint4*>(dst)     = o0;
  *reinterpret_cast<uint4*>(dst + 8) = o1;
}

// ---------------- k4: output projection Y = O @ Wo^T (fp32 out) ----------------
// Wo is [HID][HDIM] row-major: row stride HDIM=64. B-frag for output col h:
// Wob[h*HDIM + k] with k = quad*8 (+32 for the second K=32 step).
__global__ __launch_bounds__(256) void out_proj(
    const unsigned short* __restrict__ O,
    const unsigned short* __restrict__ Wob,
    float* __restrict__ Y) {
  const int nb   = blockIdx.x;
  const int mb   = blockIdx.y;
  const int lane = threadIdx.x & 63;
  const int wave = threadIdx.x >> 6;
  const int quad = lane >> 4;
  const int l15  = lane & 15;
  const int row0 = mb * 64 + wave * 16;

  f32x4 acc[4];
  const f32x4 zero = {0.f, 0.f, 0.f, 0.f};
#pragma unroll
  for (int n = 0; n < 4; ++n) acc[n] = zero;

  const unsigned short* op = O + (size_t)(row0 + l15) * HDIM + quad * 8;
  bf16x8 a0 = *reinterpret_cast<const bf16x8*>(op);
  bf16x8 a1 = *reinterpret_cast<const bf16x8*>(op + 32);
#pragma unroll
  for (int n = 0; n < 4; ++n) {
    const int col = nb * 64 + n * 16 + l15;
    const unsigned short* wp = Wob + (size_t)col * HDIM + quad * 8;   // stride HDIM (R7 fix)
    bf16x8 b0 = *reinterpret_cast<const bf16x8*>(wp);
    bf16x8 b1 = *reinterpret_cast<const bf16x8*>(wp + 32);
    acc[n] = __builtin_amdgcn_mfma_f32_16x16x32_bf16(a0, b0, acc[n], 0, 0, 0);
    acc[n] = __builtin_amdgcn_mfma_f32_16x16x32_bf16(a1, b1, acc[n], 0, 0, 0);
  }
#pragma unroll
  for (int n = 0; n < 4; ++n)
#pragma unroll
    for (int r = 0; r < 4; ++r) {
      const int row = row0 + quad * 4 + r;
      const int col = nb * 64 + n * 16 + l15;
      Y[(size_t)row * HID + col] = acc[n][r];
    }
}

extern "C" void kernel_launch(void* const* d_in, const int* in_sizes, int n_in,
                              void* d_out, int out_size, void* d_ws, size_t ws_size,
                              hipStream_t stream) {
  const float* x  = (const float*)d_in[0];
  const float* Wq = (const float*)d_in[1];
  const float* Wk = (const float*)d_in[2];
  const float* Wv = (const float*)d_in[3];
  const float* Wo = (const float*)d_in[4];
  float* Y = (float*)d_out;

  const size_t qkv_elems = (size_t)BATCH * SEQ * HDIM;       // 1M
  const size_t w_elems   = (size_t)HDIM * HID;               // 64K
  unsigned short* Q     = (unsigned short*)d_ws;
  unsigned short* K     = Q + qkv_elems;
  unsigned short* Vt    = K + qkv_elems;
  unsigned short* O     = Vt + qkv_elems;
  unsigned short* Wqb   = O + qkv_elems;
  unsigned short* Wkb   = Wqb + w_elems;
  unsigned short* Wvb   = Wkb + w_elems;
  unsigned short* Wob   = Wvb + w_elems;
  // ws use: 4x 2MB QKVO + 0.5MB weights = 8.5 MB.
  // Split-K partials live in d_out as scratch (64 MB fp32 buffer; partials
  // need 17 MB). Safe: flash writes Opart/Ml, merge reads them, then out_proj
  // (last kernel, same stream) overwrites the ENTIRE out buffer with Y.
  unsigned short* Opart = (unsigned short*)d_out;             // 2048 slots x 4096 bf16 = 16 MB
  float2*         Ml    = (float2*)(Opart + (size_t)2048 * 4096);  // 128K float2 = 1 MB

  convert_w   <<<1024,               256, 0, stream>>>(Wq, Wk, Wv, Wo, Wqb, Wkb, Wvb, Wob);
  qkv_proj    <<<512,                256, 0, stream>>>(x, Wqb, Wkb, Wvb, Q, K, Vt);
  flash_splitk<<<dim3(64, 4, NCMAX), 256, 0, stream>>>(Q, K, Vt, O, Opart, Ml);
  merge_splitk<<<dim3(64, 4),        256, 0, stream>>>(Opart, Ml, O);
  out_proj    <<<dim3(16, 256),      256, 0, stream>>>(O, Wob, Y);
}

// Round 10
// 200.362 us; speedup vs baseline: 1.2552x; 1.0133x over previous
//
#include <hip/hip_runtime.h>
#include <hip/hip_bf16.h>

// SingleHeadAttention: B=4, S=4096, H=1024, D=64. fp32 I/O, bf16 MFMA compute.
//
// k0: convert Wq/Wk/Wv/Wo fp32 -> bf16 (ws)
// k1: fused QKV proj v3: x + W staged in LDS via coalesced global_load_lds
//     (pre-swizzled global sources), K-chunk 64, double-buffered (R9: 239->203).
// k2: split-K causal flash. R10: COMPACT grid (288 active chunks, no
//     instant-exit blocks) decoded arithmetically from flat id, REVERSED so
//     longest 8-tile chunks dispatch first (LPT). R9 counters: occupancy 20%
//     from 896/2048 instant-exit blocks + long chunks in the dispatch tail.
// k3: merge partials (qb >= 8)
// k4: Y = O @ Wo^T (fp32 out). Wo row stride HDIM=64 (R7 fix).
// Opart/Ml live in d_out as scratch (flash writes, merge reads, out_proj —
// the final kernel — overwrites the entire out buffer with Y; stream-ordered).

typedef __attribute__((ext_vector_type(8))) __bf16 bf16x8;
typedef __attribute__((ext_vector_type(4))) float f32x4;

#define BATCH 4
#define SEQ   4096
#define HID   1024
#define HDIM  64
#define CHT   8           // 64-key tiles per split-K chunk
#define NCMAX 8           // max chunks per Q-tile
#define NCHUNK 288        // total active (qb,c) chunks per batch

__device__ __forceinline__ unsigned short f2bf(float f) {
  unsigned u = __builtin_bit_cast(unsigned, f);
  u += 0x7fffu + ((u >> 16) & 1u);          // RTN
  return (unsigned short)(u >> 16);
}
__device__ __forceinline__ float bf2f(unsigned short u) {
  unsigned v = ((unsigned)u) << 16;
  return __builtin_bit_cast(float, v);
}
__device__ __forceinline__ __bf16 f2bf16(float f) {
  unsigned short us = f2bf(f);
  return __builtin_bit_cast(__bf16, us);
}
__device__ __forceinline__ bf16x8 pack8(f32x4 a, f32x4 b) {
  bf16x8 r;
  r[0] = f2bf16(a[0]); r[1] = f2bf16(a[1]); r[2] = f2bf16(a[2]); r[3] = f2bf16(a[3]);
  r[4] = f2bf16(b[0]); r[5] = f2bf16(b[1]); r[6] = f2bf16(b[2]); r[7] = f2bf16(b[3]);
  return r;
}

// ---------------- k0: weight conversion ----------------
__global__ __launch_bounds__(256) void convert_w(
    const float* __restrict__ Wq, const float* __restrict__ Wk,
    const float* __restrict__ Wv, const float* __restrict__ Wo,
    unsigned short* __restrict__ q, unsigned short* __restrict__ k,
    unsigned short* __restrict__ v, unsigned short* __restrict__ o) {
  const int gid = blockIdx.x * 256 + threadIdx.x;
  const int mat = gid >> 16, idx = gid & 0xFFFF;
  const float* s = (mat == 0) ? Wq : (mat == 1) ? Wk : (mat == 2) ? Wv : Wo;
  unsigned short* d = (mat == 0) ? q : (mat == 1) ? k : (mat == 2) ? v : o;
  d[idx] = f2bf(s[idx]);
}

// ---------------- k1: fused QKV projection (x + W LDS-staged, K-chunk 64) ----
__global__ __launch_bounds__(256) void qkv_proj(
    const float* __restrict__ x,
    const unsigned short* __restrict__ Wqb,
    const unsigned short* __restrict__ Wkb,
    const unsigned short* __restrict__ Wvb,
    unsigned short* __restrict__ Q,
    unsigned short* __restrict__ K,
    unsigned short* __restrict__ Vt) {
  const int mb   = blockIdx.x;          // 32-row tile
  const int tid  = threadIdx.x;
  const int lane = tid & 63;
  const int wave = tid >> 6;
  const int quad = lane >> 4;
  const int l15  = lane & 15;
  const int rt   = wave >> 1;           // 0,1
  const int nh   = wave & 1;            // 0,1
  const int ar   = rt * 16 + l15;       // local row this lane reads for A
  const int row0 = mb * 32 + rt * 16;

  __shared__ float          xs[2][32 * 64];       // 8KB per buf
  __shared__ unsigned short wl[2][3 * 64 * 64];   // 24KB per buf

  const unsigned short* Ws[3] = {Wqb, Wkb, Wvb};

  f32x4 acc[3][2];
  const f32x4 zero = {0.f, 0.f, 0.f, 0.f};
#pragma unroll
  for (int z = 0; z < 3; ++z)
#pragma unroll
    for (int n2 = 0; n2 < 2; ++n2) acc[z][n2] = zero;

  // x: slot = j*256 + tid -> row = slot>>4, p = slot&15, src chunk = p^(row&7)
  const int xrow0 = tid >> 4;            // issue 0 row (0..15)
  const int xp    = tid & 15;
  const int xg0   = (xp & 8) | ((xp & 7) ^ (xrow0 & 7));
  const int xrow1 = xrow0 + 16;          // issue 1 row (16..31)
  const int xg1   = (xp & 8) | ((xp & 7) ^ (xrow1 & 7));
  const float* xsrc0 = x + (size_t)(mb * 32 + xrow0) * HID + xg0 * 4;
  const float* xsrc1 = x + (size_t)(mb * 32 + xrow1) * HID + xg1 * 4;
  // W: slot = j*256 + tid -> col = slot>>3, p = slot&7, src chunk = p^(col&7)
  const int wcol0 = tid >> 3;            // issue 0 col (0..31)
  const int wp    = tid & 7;
  const int wg0   = wp ^ (wcol0 & 7);
  const int wcol1 = wcol0 + 32;          // issue 1 col (32..63)
  const int wg1   = wp ^ (wcol1 & 7);

  const int swz = ar & 7;

#define STAGE_TILE(buf, kk)                                                     \
  do {                                                                          \
    float* xb = &xs[buf][wave * 256];                                           \
    __builtin_amdgcn_global_load_lds(                                           \
        (const __attribute__((address_space(1))) void*)(xsrc0 + (kk)),          \
        (__attribute__((address_space(3))) void*)xb, 16, 0, 0);                 \
    __builtin_amdgcn_global_load_lds(                                           \
        (const __attribute__((address_space(1))) void*)(xsrc1 + (kk)),          \
        (__attribute__((address_space(3))) void*)(xb + 1024), 16, 0, 0);        \
    _Pragma("unroll")                                                           \
    for (int z = 0; z < 3; ++z) {                                               \
      unsigned short* wb = &wl[buf][z * 4096 + wave * 512];                     \
      __builtin_amdgcn_global_load_lds(                                         \
          (const __attribute__((address_space(1))) void*)(                      \
              Ws[z] + (size_t)wcol0 * HID + (kk) + wg0 * 8),                    \
          (__attribute__((address_space(3))) void*)wb, 16, 0, 0);               \
      __builtin_amdgcn_global_load_lds(                                         \
          (const __attribute__((address_space(1))) void*)(                      \
              Ws[z] + (size_t)wcol1 * HID + (kk) + wg1 * 8),                    \
          (__attribute__((address_space(3))) void*)(wb + 2048), 16, 0, 0);      \
    }                                                                           \
  } while (0)

  STAGE_TILE(0, 0);

  for (int kk = 0; kk < HID; kk += 64) {
    const int buf = (kk >> 6) & 1;
    __syncthreads();                    // drains vmcnt -> tile kk visible
    if (kk + 64 < HID) STAGE_TILE(buf ^ 1, kk + 64);

#pragma unroll
    for (int sub = 0; sub < 2; ++sub) {
      const int c0 = sub * 8 + ((2 * quad)     ^ swz);
      const int c1 = sub * 8 + ((2 * quad + 1) ^ swz);
      f32x4 alo = *reinterpret_cast<const f32x4*>(&xs[buf][ar * 64 + c0 * 4]);
      f32x4 ahi = *reinterpret_cast<const f32x4*>(&xs[buf][ar * 64 + c1 * 4]);
      bf16x8 a = pack8(alo, ahi);
#pragma unroll
      for (int z = 0; z < 3; ++z)
#pragma unroll
        for (int n2 = 0; n2 < 2; ++n2) {
          const int col = nh * 32 + n2 * 16 + l15;
          const int wc  = (sub * 4 + quad) ^ (col & 7);
          bf16x8 b = *reinterpret_cast<const bf16x8*>(&wl[buf][z * 4096 + col * 64 + wc * 8]);
          acc[z][n2] = __builtin_amdgcn_mfma_f32_16x16x32_bf16(a, b, acc[z][n2], 0, 0, 0);
        }
    }
  }
#undef STAGE_TILE

  // epilogue: C layout col=l15(+offsets), row=quad*4+r
#pragma unroll
  for (int z = 0; z < 2; ++z) {
    unsigned short* Out = (z == 0) ? Q : K;
#pragma unroll
    for (int n2 = 0; n2 < 2; ++n2)
#pragma unroll
      for (int r = 0; r < 4; ++r) {
        const int row = row0 + quad * 4 + r;
        const int col = nh * 32 + n2 * 16 + l15;
        Out[(size_t)row * HDIM + col] = f2bf(acc[z][n2][r]);
      }
  }
#pragma unroll
  for (int n2 = 0; n2 < 2; ++n2)
#pragma unroll
    for (int r = 0; r < 4; ++r) {
      const int row = row0 + quad * 4 + r;          // global seq index
      const int col = nh * 32 + n2 * 16 + l15;      // dim
      const int bb = row >> 12, sl = row & 4095;
      Vt[(size_t)bb * HDIM * SEQ + (size_t)col * SEQ + sl] = f2bf(acc[2][n2][r]);
    }
}

// ---------------- k2: split-K causal flash, reg-prefetch dbuf ----------------
#define LSTR 72   // 64 + 8 pad (16B-aligned rows)

__global__ __launch_bounds__(256) void flash_splitk(
    const unsigned short* __restrict__ Qg,
    const unsigned short* __restrict__ Kg,
    const unsigned short* __restrict__ Vt,
    unsigned short* __restrict__ Og,
    unsigned short* __restrict__ Opart,
    float2* __restrict__ Ml) {
  // R10: compact grid. blockIdx.x = flat chunk id (0..287), reversed so the
  // longest chunks (high qb group) dispatch first (LPT scheduling).
  // Group g = qb>>3 has 8 qb values x (g+1) chunks; base offset 4g(g+1).
  const int s = (NCHUNK - 1) - (int)blockIdx.x;
  int g = 0, base = 0;
  while (s >= base + 8 * (g + 1)) { base += 8 * (g + 1); ++g; }
  const int idx = s - base;
  const int qb  = g * 8 + idx / (g + 1);
  const int c   = idx % (g + 1);
  const int b   = blockIdx.y;
  const int nc  = (qb >> 3) + 1;
  const int j0 = c * CHT;
  const int j1 = min(j0 + CHT, qb + 1);

  const int tid  = threadIdx.x;
  const int lane = tid & 63;
  const int wave = tid >> 6;
  const int quad = lane >> 4;
  const int l15  = lane & 15;

  __shared__ unsigned short kt[64 * LSTR];       // K tile [key][dim]
  __shared__ unsigned short vt[64 * LSTR];       // V tile [dim][key]
  __shared__ unsigned short pt[4][16 * LSTR];    // per-wave P [qrow][key]

  const size_t base_  = (size_t)b * SEQ * HDIM;
  const size_t baseT = (size_t)b * HDIM * SEQ;
  const int qrow0 = qb * 64 + wave * 16;

  bf16x8 aq[2];
  {
    const unsigned short* qp = Qg + base_ + (size_t)(qrow0 + l15) * HDIM + quad * 8;
    aq[0] = *reinterpret_cast<const bf16x8*>(qp);
    aq[1] = *reinterpret_cast<const bf16x8*>(qp + 32);
  }

  f32x4 o[4];
  const f32x4 zero = {0.f, 0.f, 0.f, 0.f};
#pragma unroll
  for (int n = 0; n < 4; ++n) o[n] = zero;
  float m_i[4], l_i[4];
#pragma unroll
  for (int r = 0; r < 4; ++r) { m_i[r] = -__builtin_inff(); l_i[r] = 0.f; }

  unsigned short* pw = pt[wave];
  const int srow = tid >> 2, sc0 = (tid & 3) * 16;   // staging coords
  const unsigned short* kb = Kg + base_;
  const unsigned short* vb = Vt + baseT;

  // softmax scale folded into exp2: p = 2^(s*C - m*C),  C = 0.125*log2(e)
  const float C = 0.125f * 1.44269504f;

  // prologue: stage tile j0
  uint4 pk0, pk1, pv0, pv1;
  {
    const uint4* kp = reinterpret_cast<const uint4*>(kb + (size_t)(j0 * 64 + srow) * HDIM + sc0);
    pk0 = kp[0]; pk1 = kp[1];
    const uint4* vp = reinterpret_cast<const uint4*>(vb + (size_t)srow * SEQ + j0 * 64 + sc0);
    pv0 = vp[0]; pv1 = vp[1];
    *reinterpret_cast<uint4*>(&kt[srow * LSTR + sc0])     = pk0;
    *reinterpret_cast<uint4*>(&kt[srow * LSTR + sc0 + 8]) = pk1;
    *reinterpret_cast<uint4*>(&vt[srow * LSTR + sc0])     = pv0;
    *reinterpret_cast<uint4*>(&vt[srow * LSTR + sc0 + 8]) = pv1;
  }

  for (int j = j0; j < j1; ++j) {
    __syncthreads();                       // publish LDS tile j
    const bool pre = (j + 1 < j1);
    if (pre) {                             // issue loads for tile j+1 now
      const uint4* kp = reinterpret_cast<const uint4*>(kb + (size_t)((j + 1) * 64 + srow) * HDIM + sc0);
      pk0 = kp[0]; pk1 = kp[1];
      const uint4* vp = reinterpret_cast<const uint4*>(vb + (size_t)srow * SEQ + (j + 1) * 64 + sc0);
      pv0 = vp[0]; pv1 = vp[1];
    }

    f32x4 s4[4];
#pragma unroll
    for (int n = 0; n < 4; ++n) s4[n] = zero;
#pragma unroll
    for (int ks = 0; ks < 2; ++ks) {
#pragma unroll
      for (int n = 0; n < 4; ++n) {
        bf16x8 bk = *reinterpret_cast<const bf16x8*>(&kt[(n * 16 + l15) * LSTR + ks * 32 + quad * 8]);
        s4[n] = __builtin_amdgcn_mfma_f32_16x16x32_bf16(aq[ks], bk, s4[n], 0, 0, 0);
      }
    }

    if (j == qb) {                         // causal mask (raw-score units)
#pragma unroll
      for (int n = 0; n < 4; ++n) {
        const int col = n * 16 + l15;
#pragma unroll
        for (int r = 0; r < 4; ++r) {
          const int rowl = wave * 16 + quad * 4 + r;
          if (col > rowl) s4[n][r] = -__builtin_inff();
        }
      }
    }

    float mnew[4], alpha[4], mC[4];
#pragma unroll
    for (int r = 0; r < 4; ++r) {
      float v = fmaxf(fmaxf(s4[0][r], s4[1][r]), fmaxf(s4[2][r], s4[3][r]));
#pragma unroll
      for (int off = 1; off < 16; off <<= 1) v = fmaxf(v, __shfl_xor(v, off, 64));
      mnew[r]  = fmaxf(m_i[r], v);
      alpha[r] = __builtin_amdgcn_exp2f((m_i[r] - mnew[r]) * C);
      mC[r]    = mnew[r] * C;
    }
    float p[4][4];
#pragma unroll
    for (int n = 0; n < 4; ++n)
#pragma unroll
      for (int r = 0; r < 4; ++r)
        p[n][r] = __builtin_amdgcn_exp2f(__builtin_fmaf(s4[n][r], C, -mC[r]));
#pragma unroll
    for (int r = 0; r < 4; ++r) {
      float v = (p[0][r] + p[1][r]) + (p[2][r] + p[3][r]);
#pragma unroll
      for (int off = 1; off < 16; off <<= 1) v += __shfl_xor(v, off, 64);
      l_i[r] = l_i[r] * alpha[r] + v;
      m_i[r] = mnew[r];
    }
#pragma unroll
    for (int n = 0; n < 4; ++n)
#pragma unroll
      for (int r = 0; r < 4; ++r) o[n][r] *= alpha[r];

#pragma unroll
    for (int n = 0; n < 4; ++n)
#pragma unroll
      for (int r = 0; r < 4; ++r)
        pw[(quad * 4 + r) * LSTR + n * 16 + l15] = f2bf(p[n][r]);

#pragma unroll
    for (int ks = 0; ks < 2; ++ks) {
      bf16x8 ap = *reinterpret_cast<const bf16x8*>(&pw[l15 * LSTR + ks * 32 + quad * 8]);
#pragma unroll
      for (int n = 0; n < 4; ++n) {
        bf16x8 bv = *reinterpret_cast<const bf16x8*>(&vt[(n * 16 + l15) * LSTR + ks * 32 + quad * 8]);
        o[n] = __builtin_amdgcn_mfma_f32_16x16x32_bf16(ap, bv, o[n], 0, 0, 0);
      }
    }

    __syncthreads();                       // all waves done reading kt/vt
    if (pre) {                             // drain prefetch into LDS
      *reinterpret_cast<uint4*>(&kt[srow * LSTR + sc0])     = pk0;
      *reinterpret_cast<uint4*>(&kt[srow * LSTR + sc0 + 8]) = pk1;
      *reinterpret_cast<uint4*>(&vt[srow * LSTR + sc0])     = pv0;
      *reinterpret_cast<uint4*>(&vt[srow * LSTR + sc0 + 8]) = pv1;
    }
  }

  if (nc == 1) {
#pragma unroll
    for (int n = 0; n < 4; ++n)
#pragma unroll
      for (int r = 0; r < 4; ++r) {
        const int row = qrow0 + quad * 4 + r;
        const int col = n * 16 + l15;
        Og[base_ + (size_t)row * HDIM + col] = f2bf(o[n][r] / l_i[r]);
      }
  } else {
    const int slot = ((b * 64 + qb) << 3) + c;
#pragma unroll
    for (int n = 0; n < 4; ++n)
#pragma unroll
      for (int r = 0; r < 4; ++r) {
        const int rowl = wave * 16 + quad * 4 + r;
        const int col  = n * 16 + l15;
        Opart[(size_t)slot * 4096 + rowl * 64 + col] = f2bf(o[n][r]);
      }
    if (l15 == 0) {
#pragma unroll
      for (int r = 0; r < 4; ++r) {
        const int rowl = wave * 16 + quad * 4 + r;
        Ml[slot * 64 + rowl] = make_float2(m_i[r], l_i[r]);
      }
    }
  }
}

// ---------------- k3: merge split-K partials (qb >= 8) ----------------
__global__ __launch_bounds__(256) void merge_splitk(
    const unsigned short* __restrict__ Opart,
    const float2* __restrict__ Ml,
    unsigned short* __restrict__ Og) {
  const int qb = blockIdx.x;
  if (qb < CHT) return;
  const int b  = blockIdx.y;
  const int nc = (qb >> 3) + 1;
  const int row = threadIdx.x >> 2;
  const int cg  = (threadIdx.x & 3) * 16;
  const int slot0 = (b * 64 + qb) << 3;

  float m[NCMAX], l[NCMAX];
  float M = -__builtin_inff();
  for (int c = 0; c < nc; ++c) {
    float2 ml = Ml[(slot0 + c) * 64 + row];
    m[c] = ml.x; l[c] = ml.y;
    M = fmaxf(M, m[c]);
  }
  const float C = 0.125f * 1.44269504f;
  float L = 0.f, acc[16];
#pragma unroll
  for (int i = 0; i < 16; ++i) acc[i] = 0.f;
  for (int c = 0; c < nc; ++c) {
    const float w = __builtin_amdgcn_exp2f((m[c] - M) * C);
    L += w * l[c];
    const unsigned short* p = Opart + (size_t)(slot0 + c) * 4096 + row * 64 + cg;
    uint4 u0 = *reinterpret_cast<const uint4*>(p);
    uint4 u1 = *reinterpret_cast<const uint4*>(p + 8);
    const unsigned* uu = &u0.x;
#pragma unroll
    for (int i = 0; i < 4; ++i) {
      acc[2 * i]     += w * bf2f((unsigned short)(uu[i] & 0xFFFF));
      acc[2 * i + 1] += w * bf2f((unsigned short)(uu[i] >> 16));
    }
    const unsigned* vv = &u1.x;
#pragma unroll
    for (int i = 0; i < 4; ++i) {
      acc[8 + 2 * i]     += w * bf2f((unsigned short)(vv[i] & 0xFFFF));
      acc[8 + 2 * i + 1] += w * bf2f((unsigned short)(vv[i] >> 16));
    }
  }
  const float inv = 1.f / L;
  uint4 o0, o1;
  unsigned* po = &o0.x;
#pragma unroll
  for (int i = 0; i < 4; ++i)
    po[i] = (unsigned)f2bf(acc[2 * i] * inv) | ((unsigned)f2bf(acc[2 * i + 1] * inv) << 16);
  unsigned* p1 = &o1.x;
#pragma unroll
  for (int i = 0; i < 4; ++i)
    p1[i] = (unsigned)f2bf(acc[8 + 2 * i] * inv) | ((unsigned)f2bf(acc[8 + 2 * i + 1] * inv) << 16);
  unsigned short* dst = Og + (size_t)b * SEQ * HDIM + (size_t)(qb * 64 + row) * HDIM + cg;
  *reinterpret_cast<uint4*>(dst)     = o0;
  *reinterpret_cast<uint4*>(dst + 8) = o1;
}

// ---------------- k4: output projection Y = O @ Wo^T (fp32 out) ----------------
// Wo is [HID][HDIM] row-major: row stride HDIM=64.
__global__ __launch_bounds__(256) void out_proj(
    const unsigned short* __restrict__ O,
    const unsigned short* __restrict__ Wob,
    float* __restrict__ Y) {
  const int nb   = blockIdx.x;
  const int mb   = blockIdx.y;
  const int lane = threadIdx.x & 63;
  const int wave = threadIdx.x >> 6;
  const int quad = lane >> 4;
  const int l15  = lane & 15;
  const int row0 = mb * 64 + wave * 16;

  f32x4 acc[4];
  const f32x4 zero = {0.f, 0.f, 0.f, 0.f};
#pragma unroll
  for (int n = 0; n < 4; ++n) acc[n] = zero;

  const unsigned short* op = O + (size_t)(row0 + l15) * HDIM + quad * 8;
  bf16x8 a0 = *reinterpret_cast<const bf16x8*>(op);
  bf16x8 a1 = *reinterpret_cast<const bf16x8*>(op + 32);
#pragma unroll
  for (int n = 0; n < 4; ++n) {
    const int col = nb * 64 + n * 16 + l15;
    const unsigned short* wp = Wob + (size_t)col * HDIM + quad * 8;   // stride HDIM (R7 fix)
    bf16x8 b0 = *reinterpret_cast<const bf16x8*>(wp);
    bf16x8 b1 = *reinterpret_cast<const bf16x8*>(wp + 32);
    acc[n] = __builtin_amdgcn_mfma_f32_16x16x32_bf16(a0, b0, acc[n], 0, 0, 0);
    acc[n] = __builtin_amdgcn_mfma_f32_16x16x32_bf16(a1, b1, acc[n], 0, 0, 0);
  }
#pragma unroll
  for (int n = 0; n < 4; ++n)
#pragma unroll
    for (int r = 0; r < 4; ++r) {
      const int row = row0 + quad * 4 + r;
      const int col = nb * 64 + n * 16 + l15;
      Y[(size_t)row * HID + col] = acc[n][r];
    }
}

extern "C" void kernel_launch(void* const* d_in, const int* in_sizes, int n_in,
                              void* d_out, int out_size, void* d_ws, size_t ws_size,
                              hipStream_t stream) {
  const float* x  = (const float*)d_in[0];
  const float* Wq = (const float*)d_in[1];
  const float* Wk = (const float*)d_in[2];
  const float* Wv = (const float*)d_in[3];
  const float* Wo = (const float*)d_in[4];
  float* Y = (float*)d_out;

  const size_t qkv_elems = (size_t)BATCH * SEQ * HDIM;       // 1M
  const size_t w_elems   = (size_t)HDIM * HID;               // 64K
  unsigned short* Q     = (unsigned short*)d_ws;
  unsigned short* K     = Q + qkv_elems;
  unsigned short* Vt    = K + qkv_elems;
  unsigned short* O     = Vt + qkv_elems;
  unsigned short* Wqb   = O + qkv_elems;
  unsigned short* Wkb   = Wqb + w_elems;
  unsigned short* Wvb   = Wkb + w_elems;
  unsigned short* Wob   = Wvb + w_elems;
  // ws use: 4x 2MB QKVO + 0.5MB weights = 8.5 MB.
  // Split-K partials live in d_out as scratch (64 MB fp32 buffer; partials
  // need 17 MB). Safe: flash writes Opart/Ml, merge reads them, then out_proj
  // (last kernel, same stream) overwrites the ENTIRE out buffer with Y.
  unsigned short* Opart = (unsigned short*)d_out;             // 2048 slots x 4096 bf16 = 16 MB
  float2*         Ml    = (float2*)(Opart + (size_t)2048 * 4096);  // 128K float2 = 1 MB

  convert_w   <<<1024,                256, 0, stream>>>(Wq, Wk, Wv, Wo, Wqb, Wkb, Wvb, Wob);
  qkv_proj    <<<512,                 256, 0, stream>>>(x, Wqb, Wkb, Wvb, Q, K, Vt);
  flash_splitk<<<dim3(NCHUNK, BATCH), 256, 0, stream>>>(Q, K, Vt, O, Opart, Ml);
  merge_splitk<<<dim3(64, 4),         256, 0, stream>>>(Opart, Ml, O);
  out_proj    <<<dim3(16, 256),       256, 0, stream>>>(O, Wob, Y);
}